// Round 13
// baseline (277.921 us; speedup 1.0000x reference)
//
#include <hip/hip_runtime.h>
#include <hip/hip_fp8.h>

// ---------------------------------------------------------------------------
// Debiased Representation Loss — fused MI355X implementation (R13).
// R12 fp8 main kernel (conflict-free half-swap layout) reduced to a 2-node
// graph: per-row partials go through 64 KB rowacc[4096][4] via device-scope
// atomicAdd (replaces the 4 MB partials round-trip), and the last-finishing
// main_fused block performs the whole row-reduce + entropy finalize.
//   1) pre_all: normalize->fp8 (+rowacc zero) | softmax partials (+accums
//      zero) | fz GEMM (512 x 64x64 tiles, f32 in, fp8 out) — one launch.
//   2) main_fused: fp8 contrastive + last-block finalize -> d_out[0].
// ---------------------------------------------------------------------------

#define B_N   4096
#define D_N   768
#define HID_N 256
#define NCLS  200

typedef __attribute__((ext_vector_type(8))) short v8s;   // 8 x bf16 (4 VGPRs)
typedef __attribute__((ext_vector_type(4))) float v4f;   // MFMA accumulator

// round-to-nearest-even fp32 -> bf16
__device__ __forceinline__ unsigned short f2bf(float x) {
    unsigned int u = __float_as_uint(x);
    unsigned int r = (u + 0x7FFFu + ((u >> 16) & 1u)) >> 16;
    return (unsigned short)r;
}
__device__ __forceinline__ float bf2f(unsigned short h) {
    return __uint_as_float((unsigned int)h << 16);
}
// fp32 -> OCP e4m3 (RNE, saturating)
__device__ __forceinline__ unsigned char f2fp8(float x) {
    __hip_fp8_e4m3 v(x);
    return (unsigned char)v.__x;
}

// async global->LDS, 16 B per lane
__device__ __forceinline__ void gld16c(const unsigned char* g, unsigned char* l) {
    __builtin_amdgcn_global_load_lds(
        (__attribute__((address_space(1))) void*)g,
        (__attribute__((address_space(3))) void*)l, 16, 0, 0);
}

#define ZERO_ACC(a) { _Pragma("unroll") for (int _i = 0; _i < 4; _i++) \
    _Pragma("unroll") for (int _j = 0; _j < 4; _j++) a[_i][_j] = (v4f){0.f,0.f,0.f,0.f}; }

// ---------------------------------------------------------------------------
// Kernel 1: pre_all — three independent block families.
//  [0,4096)    : L2-normalize row -> zn8/bn8 fp8 (x16, half-swapped); zero
//                rowacc[row][0..3]
//  [4096,4352) : softmax partials (block 4096 zeroes accums[0..3])
//  [4352,4864) : fz = z@W^T+b, 64x64 tiles, f32 in (inline bf16), fp8 out (x4)
// ---------------------------------------------------------------------------
__global__ __launch_bounds__(256) void pre_all(
    const float* __restrict__ z, const float* __restrict__ base,
    const float* __restrict__ w1, const float* __restrict__ w2,
    const float* __restrict__ b1, const float* __restrict__ b2,
    const float* __restrict__ logits, const int* __restrict__ oldi,
    const int* __restrict__ newi,
    unsigned char* __restrict__ zn8, unsigned char* __restrict__ bn8,
    unsigned char* __restrict__ f1z8, unsigned char* __restrict__ f2z8,
    float* __restrict__ mpart, float* __restrict__ rowacc,
    float* __restrict__ accums)
{
    __shared__ __align__(16) unsigned char shmem[2 * 64 * 72 * 2];  // 18.4 KB
    int tid = threadIdx.x;

    if (blockIdx.x < B_N) {
        // ---- normalize ----
        float* ws1 = (float*)shmem;
        float* ws2 = ws1 + 4;
        int row = blockIdx.x;
        if (tid == 0) *(float4*)(rowacc + (size_t)row * 4) = make_float4(0.f, 0.f, 0.f, 0.f);
        const float* zr = z    + (size_t)row * D_N;
        const float* br = base + (size_t)row * D_N;
        float z0 = zr[tid], z1 = zr[tid + 256], z2 = zr[tid + 512];
        float b0 = br[tid], b1v = br[tid + 256], b2v = br[tid + 512];
        float s1 = z0*z0 + z1*z1 + z2*z2;
        float s2 = b0*b0 + b1v*b1v + b2v*b2v;
        #pragma unroll
        for (int m = 32; m > 0; m >>= 1) { s1 += __shfl_xor(s1, m); s2 += __shfl_xor(s2, m); }
        if ((tid & 63) == 0) { ws1[tid >> 6] = s1; ws2[tid >> 6] = s2; }
        __syncthreads();
        float t1 = ws1[0] + ws1[1] + ws1[2] + ws1[3];
        float t2 = ws2[0] + ws2[1] + ws2[2] + ws2[3];
        float sc1 = 16.0f / fmaxf(sqrtf(t1), 1e-12f);
        float sc2 = 16.0f / fmaxf(sqrtf(t2), 1e-12f);
        size_t o = (size_t)row * D_N;
        int j0 = tid ^ (((row >> 3) & 1) << 3);        // half-swap key
        zn8[o+j0] = f2fp8(z0*sc1);  zn8[o+j0+256] = f2fp8(z1*sc1);  zn8[o+j0+512] = f2fp8(z2*sc1);
        bn8[o+j0] = f2fp8(b0*sc2);  bn8[o+j0+256] = f2fp8(b1v*sc2); bn8[o+j0+512] = f2fp8(b2v*sc2);
        return;
    }
    if (blockIdx.x < B_N + 256) {
        // ---- softmax partials: 256 blocks x 16 rows ----
        int* act = (int*)shmem;
        float* accs = (float*)(shmem + 1024);          // [4][256]
        int sb = blockIdx.x - B_N;
        int lane = tid & 63, wave = tid >> 6;
        if (sb == 0 && tid < 4) accums[tid] = 0.0f;
        if (tid < NCLS) act[tid] = (tid < 100) ? oldi[tid] : newi[tid - 100];
        accs[tid] = 0.f; accs[256 + tid] = 0.f; accs[512 + tid] = 0.f; accs[768 + tid] = 0.f;
        __syncthreads();
        int a0 = act[lane], a1 = act[lane + 64], a2 = act[lane + 128];
        int a3 = (lane < 8) ? act[lane + 192] : 0;
        int r0 = sb * 16 + wave * 4;
        float c0 = 0.f, c1 = 0.f, c2 = 0.f, c3 = 0.f;
        for (int i = 0; i < 4; i++) {
            const float* lr = logits + (size_t)(r0 + i) * NCLS;
            float x0 = lr[a0], x1 = lr[a1], x2 = lr[a2];
            float x3 = (lane < 8) ? lr[a3] : -3.0e38f;
            float m = fmaxf(fmaxf(x0, x1), fmaxf(x2, x3));
            #pragma unroll
            for (int s = 32; s > 0; s >>= 1) m = fmaxf(m, __shfl_xor(m, s));
            float e0 = __expf(x0 - m), e1 = __expf(x1 - m), e2 = __expf(x2 - m);
            float e3 = (lane < 8) ? __expf(x3 - m) : 0.f;
            float sm = e0 + e1 + e2 + e3;
            #pragma unroll
            for (int s = 32; s > 0; s >>= 1) sm += __shfl_xor(sm, s);
            float inv = 1.0f / sm;
            c0 += e0 * inv; c1 += e1 * inv; c2 += e2 * inv; c3 += e3 * inv;
        }
        accs[wave * 256 + lane] = c0; accs[wave * 256 + lane + 64] = c1;
        accs[wave * 256 + lane + 128] = c2;
        if (lane < 8) accs[wave * 256 + lane + 192] = c3;
        __syncthreads();
        mpart[(size_t)tid * 256 + sb] =
            accs[tid] + accs[256 + tid] + accs[512 + tid] + accs[768 + tid];
        return;
    }
    // ---- fz GEMM: 512 blocks, 64x64 tiles, K=768 ----
    {
        unsigned short* Al = (unsigned short*)shmem;           // 64 x 72
        unsigned short* Bl = Al + 64 * 72;
        int f = blockIdx.x - (B_N + 256);
        int which = f >> 8;                  // 0: f1, 1: f2
        int t6 = f & 255;
        int mBase = (t6 >> 2) * 64;
        int nBase = (t6 & 3) * 64;
        const float* wsrc = which ? w2 : w1;
        const float* bias = which ? b2 : b1;
        unsigned char* outz = which ? f2z8 : f1z8;
        int lane = tid & 63, wave = tid >> 6, quad = lane >> 4, col = lane & 15;
        v4f acc[4];
        #pragma unroll
        for (int i = 0; i < 4; i++) acc[i] = (v4f){0.f, 0.f, 0.f, 0.f};
        for (int kc = 0; kc < D_N; kc += 64) {
            __syncthreads();
            #pragma unroll
            for (int s = 0; s < 4; s++) {
                int slot = s * 256 + tid;
                int row = slot >> 4, k4 = slot & 15;
                float4 va = *(const float4*)(z + (size_t)(mBase + row) * D_N + kc + k4 * 4);
                float4 vb = *(const float4*)(wsrc + (size_t)(nBase + row) * D_N + kc + k4 * 4);
                unsigned short* pa = Al + row * 72 + k4 * 4;
                unsigned short* pb = Bl + row * 72 + k4 * 4;
                pa[0] = f2bf(va.x); pa[1] = f2bf(va.y); pa[2] = f2bf(va.z); pa[3] = f2bf(va.w);
                pb[0] = f2bf(vb.x); pb[1] = f2bf(vb.y); pb[2] = f2bf(vb.z); pb[3] = f2bf(vb.w);
            }
            __syncthreads();
            #pragma unroll
            for (int kk = 0; kk < 2; kk++) {
                v8s af = *(const v8s*)(Al + (wave * 16 + col) * 72 + kk * 32 + quad * 8);
                #pragma unroll
                for (int tc = 0; tc < 4; tc++) {
                    v8s bf = *(const v8s*)(Bl + (tc * 16 + col) * 72 + kk * 32 + quad * 8);
                    acc[tc] = __builtin_amdgcn_mfma_f32_16x16x32_bf16(af, bf, acc[tc], 0, 0, 0);
                }
            }
        }
        #pragma unroll
        for (int tc = 0; tc < 4; tc++) {
            int gcol = nBase + tc * 16 + col;
            float bv = bias[gcol];
            #pragma unroll
            for (int reg = 0; reg < 4; reg++) {
                int grow = mBase + wave * 16 + quad * 4 + reg;
                int sw8 = ((grow >> 3) & 1) << 3;      // half-swap key
                outz[(size_t)grow * HID_N + (gcol ^ sw8)] =
                    f2fp8(4.0f * (acc[tc][reg] + bv));
            }
        }
    }
}

// ---------------------------------------------------------------------------
// Kernel 2: fused contrastive main, fp8 + last-block finalize. grid (32, 32).
// ---------------------------------------------------------------------------
__global__ __launch_bounds__(256, 2) void main_fused(
    const unsigned char* __restrict__ zn8, const unsigned char* __restrict__ bn8,
    const unsigned char* __restrict__ f1z8, const unsigned char* __restrict__ f2z8,
    float* __restrict__ rowacc, const float* __restrict__ mpart,
    float* __restrict__ accums, float* __restrict__ out)
{
    __shared__ __align__(16) unsigned char S[4 * 128 * 128];   // 64 KB
    unsigned char* S0 = S;
    unsigned char* S1 = S + 1 * 128 * 128;
    unsigned char* S2 = S + 2 * 128 * 128;
    unsigned char* S3 = S + 3 * 128 * 128;
    int tid = threadIdx.x, lane = tid & 63, wave = tid >> 6, quad = lane >> 4, col = lane & 15;
    int wr = wave >> 1, wc = wave & 1;
    int ib = blockIdx.x, jc = blockIdx.y;
    int rBase = ib * 128 + wr * 64;
    int cBase = jc * 128 + wc * 64;
    const int r8 = lane >> 3;
    const int kbl8 = (lane & 7) ^ r8;    // MS staging granule (16B) swizzle
    const int sub8 = ((quad & 1) ^ (col >> 3)) << 3;   // conflict-free sub-slot

    // ===== MS: mask (bn8) + sim (zn8), K=768 in 6 chunks of 128 =====
    v4f accB[4][4], accS[4][4];
    ZERO_ACC(accB); ZERO_ACC(accS);
    for (int kc = 0; kc < D_N; kc += 128) {
        __syncthreads();
        #pragma unroll
        for (int s = 0; s < 4; s++) {
            int rowbase = s * 32 + wave * 8;
            size_t rOff = (size_t)(ib * 128 + rowbase + r8) * D_N + kc + kbl8 * 16;
            size_t cOff = (size_t)(jc * 128 + rowbase + r8) * D_N + kc + kbl8 * 16;
            gld16c(bn8 + rOff, S0 + rowbase * 128);
            gld16c(bn8 + cOff, S1 + rowbase * 128);
            gld16c(zn8 + rOff, S2 + rowbase * 128);
            gld16c(zn8 + cOff, S3 + rowbase * 128);
        }
        __syncthreads();
        #pragma unroll
        for (int kk = 0; kk < 4; kk++) {
            int gbase = kk * 2 + (quad >> 1);
            int off = ((gbase ^ (col & 7)) << 4) + sub8;
            long a1[4], b1[4], a2[4], b2[4];
            #pragma unroll
            for (int t = 0; t < 4; t++) {
                int rA = (wr * 64 + t * 16 + col) * 128;
                int rB = (wc * 64 + t * 16 + col) * 128;
                a1[t] = *(const long*)(S0 + rA + off);
                b1[t] = *(const long*)(S1 + rB + off);
                a2[t] = *(const long*)(S2 + rA + off);
                b2[t] = *(const long*)(S3 + rB + off);
            }
            #pragma unroll
            for (int tr = 0; tr < 4; tr++)
                #pragma unroll
                for (int tc = 0; tc < 4; tc++) {
                    accB[tr][tc] = __builtin_amdgcn_mfma_f32_16x16x32_fp8_fp8(
                        a1[tr], b1[tc], accB[tr][tc], 0, 0, 0);
                    accS[tr][tc] = __builtin_amdgcn_mfma_f32_16x16x32_fp8_fp8(
                        a2[tr], b2[tc], accS[tr][tc], 0, 0, 0);
                }
        }
    }

    // ===== issue attn staging DMAs; epilogue VALU overlaps the DMA =====
    unsigned char* F1 = S0;               // 128 rows x 256 B
    unsigned char* F2 = S0 + 32768;
    __syncthreads();                      // all MS LDS reads complete
    {
        int r4 = lane >> 4;
        #pragma unroll
        for (int s = 0; s < 8; s++) {
            int rowbase = s * 16 + wave * 4;
            int row = rowbase + r4;
            int kb = (lane & 15) ^ (row & 15);
            gld16c(f1z8 + (size_t)(ib * 128 + row) * HID_N + kb * 16, F1 + rowbase * 256);
            gld16c(f2z8 + (size_t)(jc * 128 + row) * HID_N + kb * 16, F2 + rowbase * 256);
        }
    }

    // mask bits from accB (scale 16x16=256: threshold 0.05*256 = 12.8)
    unsigned long long mb = 0ull;
    #pragma unroll
    for (int tr = 0; tr < 4; tr++)
        #pragma unroll
        for (int tc = 0; tc < 4; tc++)
            #pragma unroll
            for (int reg = 0; reg < 4; reg++) {
                int grow = rBase + tr * 16 + quad * 4 + reg;
                int gcol = cBase + tc * 16 + col;
                if (accB[tr][tc][reg] > 12.8f && grow != gcol)
                    mb |= 1ull << (tr * 16 + tc * 4 + reg);
            }

    // dsum + packed bf16 sim values from accS (descale 1/256)
    float dsum[16];
    #pragma unroll
    for (int i = 0; i < 16; i++) dsum[i] = 0.f;
    unsigned int svp[4][4][2];
    #pragma unroll
    for (int tr = 0; tr < 4; tr++)
        #pragma unroll
        for (int tc = 0; tc < 4; tc++) {
            float s0 = accS[tr][tc][0] * 0.00390625f;
            float s1 = accS[tr][tc][1] * 0.00390625f;
            float s2 = accS[tr][tc][2] * 0.00390625f;
            float s3 = accS[tr][tc][3] * 0.00390625f;
            float svv[4] = {s0, s1, s2, s3};
            #pragma unroll
            for (int reg = 0; reg < 4; reg++) {
                int grow = rBase + tr * 16 + quad * 4 + reg;
                int gcol = cBase + tc * 16 + col;
                if (grow != gcol) dsum[tr * 4 + reg] += __expf(svv[reg] * 10.0f);
            }
            svp[tr][tc][0] = ((unsigned int)f2bf(s1) << 16) | f2bf(s0);
            svp[tr][tc][1] = ((unsigned int)f2bf(s3) << 16) | f2bf(s2);
        }

    // ===== attn: f1z8[ib] . f2z8[jc]^T, K=256 fully staged =====
    v4f accA[4][4]; ZERO_ACC(accA);
    __syncthreads();                      // DMA drained
    #pragma unroll
    for (int kk = 0; kk < 8; kk++) {
        int gbase = kk * 2 + (quad >> 1);
        int off = ((gbase ^ col) << 4) + sub8;
        long af[4], bf[4];
        #pragma unroll
        for (int t = 0; t < 4; t++) {
            af[t] = *(const long*)(F1 + (wr * 64 + t * 16 + col) * 256 + off);
            bf[t] = *(const long*)(F2 + (wc * 64 + t * 16 + col) * 256 + off);
        }
        #pragma unroll
        for (int tr = 0; tr < 4; tr++)
            #pragma unroll
            for (int tc = 0; tc < 4; tc++)
                accA[tr][tc] = __builtin_amdgcn_mfma_f32_16x16x32_fp8_fp8(
                    af[tr], bf[tc], accA[tr][tc], 0, 0, 0);
    }

    // ===== combine (attn scale 4x4=16: exp(acc/16)) =====
    float lsum[16], asum[16], nnf[16];
    #pragma unroll
    for (int i = 0; i < 16; i++) { lsum[i] = 0.f; asum[i] = 0.f; nnf[i] = 0.f; }
    #pragma unroll
    for (int tr = 0; tr < 4; tr++)
        #pragma unroll
        for (int tc = 0; tc < 4; tc++)
            #pragma unroll
            for (int reg = 0; reg < 4; reg++) {
                if ((mb >> (tr * 16 + tc * 4 + reg)) & 1ull) {
                    int slot = tr * 4 + reg;
                    float e = __expf(accA[tr][tc][reg] * 0.0625f);
                    unsigned int pk = svp[tr][tc][reg >> 1];
                    float sv = bf2f((unsigned short)((reg & 1) ? (pk >> 16) : (pk & 0xFFFF)));
                    lsum[slot] += e;
                    asum[slot] += e * sv;
                    nnf[slot] += 1.f;
                }
            }

    #pragma unroll
    for (int i = 0; i < 16; i++) {
        #pragma unroll
        for (int m = 1; m < 16; m <<= 1) {
            lsum[i] += __shfl_xor(lsum[i], m);
            asum[i] += __shfl_xor(asum[i], m);
            dsum[i] += __shfl_xor(dsum[i], m);
            nnf[i]  += __shfl_xor(nnf[i], m);
        }
        if (col == 0) {
            int row = rBase + (i >> 2) * 16 + quad * 4 + (i & 3);
            float* rp = rowacc + (size_t)row * 4;
            atomicAdd(rp + 0, lsum[i]);
            atomicAdd(rp + 1, asum[i]);
            atomicAdd(rp + 2, dsum[i]);
            atomicAdd(rp + 3, nnf[i]);
        }
    }

    // ===== last-finishing block: full finalize -> out[0] =====
    __threadfence();
    __shared__ int amLast;
    if (tid == 0) {
        int old = atomicAdd((int*)&accums[2], 1);
        amLast = (old == (int)(gridDim.x * gridDim.y) - 1);
    }
    __syncthreads();
    if (!amLast) return;

    float* red = (float*)S;               // reuse staging LDS
    float* r2s = red + 256;

    // per-row contrastive terms (agent-scope loads: atomics came from other XCDs)
    float lsumT = 0.f, cntT = 0.f;
    for (int k = 0; k < 16; k++) {
        int row = tid + k * 256;
        float* rp = rowacc + (size_t)row * 4;
        float L  = __hip_atomic_load(rp + 0, __ATOMIC_RELAXED, __HIP_MEMORY_SCOPE_AGENT);
        float A  = __hip_atomic_load(rp + 1, __ATOMIC_RELAXED, __HIP_MEMORY_SCOPE_AGENT);
        float Dn = __hip_atomic_load(rp + 2, __ATOMIC_RELAXED, __HIP_MEMORY_SCOPE_AGENT);
        float NN = __hip_atomic_load(rp + 3, __ATOMIC_RELAXED, __HIP_MEMORY_SCOPE_AGENT);
        if (NN > 0.5f) {
            lsumT += (logf(Dn + 1e-8f) - 10.0f * (A / L)) / NN;
            cntT += 1.f;
        }
    }
    red[tid] = lsumT; r2s[tid] = cntT; __syncthreads();
    for (int s = 128; s > 0; s >>= 1) {
        if (tid < s) { red[tid] += red[tid + s]; r2s[tid] += r2s[tid + s]; }
        __syncthreads();
    }
    float lcn = red[0], lcd = r2s[0];
    __syncthreads();

    // entropy from mpart (written by pre_all; kernel boundary = visible)
    float pcl = 0.0f;
    if (tid < NCLS) {
        const float4* mp = (const float4*)(mpart + (size_t)tid * 256);
        float s = 0.f;
        #pragma unroll
        for (int c = 0; c < 64; c++) { float4 v = mp[c]; s += v.x + v.y + v.z + v.w; }
        pcl = s * (1.0f / 4096.0f);
    }
    red[tid] = (tid < 100) ? pcl : 0.0f; __syncthreads();
    for (int s = 128; s > 0; s >>= 1) { if (tid < s) red[tid] += red[tid + s]; __syncthreads(); }
    float p_old = red[0]; __syncthreads();
    red[tid] = (tid >= 100 && tid < NCLS) ? pcl : 0.0f; __syncthreads();
    for (int s = 128; s > 0; s >>= 1) { if (tid < s) red[tid] += red[tid + s]; __syncthreads(); }
    float p_new = red[0]; __syncthreads();

    float t = 0.0f;
    if (tid < 100)       { float q = pcl / (p_old + 1e-8f); t = q * logf(q + 1e-8f); }
    else if (tid < NCLS) { float q = pcl / (p_new + 1e-8f); t = q * logf(q + 1e-8f); }
    red[tid] = t; __syncthreads();
    for (int s = 128; s > 0; s >>= 1) { if (tid < s) red[tid] += red[tid + s]; __syncthreads(); }

    if (tid == 0) {
        float loss_inter = p_old * logf(p_old + 1e-8f) + p_new * logf(p_new + 1e-8f)
                           + 0.69314718056f;
        float loss_entropy = loss_inter + red[0] + 2.0f * 4.60517018599f;
        float lc = (lcd > 0.5f) ? lcn / lcd : 0.0f;
        out[0] = loss_entropy + lc;
    }
}

// ---------------------------------------------------------------------------
extern "C" void kernel_launch(void* const* d_in, const int* in_sizes, int n_in,
                              void* d_out, int out_size, void* d_ws, size_t ws_size,
                              hipStream_t stream)
{
    const float* z_u    = (const float*)d_in[0];
    const float* logits = (const float*)d_in[1];
    const int*   oldi   = (const int*)d_in[2];
    const int*   newi   = (const int*)d_in[3];
    const float* basef  = (const float*)d_in[4];
    const float* f1w    = (const float*)d_in[5];
    const float* f1b    = (const float*)d_in[6];
    const float* f2w    = (const float*)d_in[7];
    const float* f2b    = (const float*)d_in[8];
    float* out = (float*)d_out;

    unsigned char* zn8   = (unsigned char*)d_ws;           // [B][D] fp8
    unsigned char* bn8   = zn8 + (size_t)B_N * D_N;
    unsigned char* f1z8  = bn8 + (size_t)B_N * D_N;        // [B][HID] fp8
    unsigned char* f2z8  = f1z8 + (size_t)B_N * HID_N;
    float* rowacc = (float*)(f2z8 + (size_t)B_N * HID_N);  // [B][4]
    float* mpart  = rowacc + (size_t)B_N * 4;              // [256 class][256 blk]
    float* accums = mpart + 256 * 256;                     // [2] + counter

    pre_all<<<B_N + 256 + 512, 256, 0, stream>>>(
        z_u, basef, f1w, f2w, f1b, f2b, logits, oldi, newi,
        zn8, bn8, f1z8, f2z8, mpart, rowacc, accums);
    main_fused<<<dim3(32, 32), 256, 0, stream>>>(zn8, bn8, f1z8, f2z8,
                                                 rowacc, mpart, accums, out);
}